// Round 8
// baseline (2274.886 us; speedup 1.0000x reference)
//
#include <hip/hip_runtime.h>
#include <hip/hip_bf16.h>

typedef float f32;
typedef __hip_bfloat16 bf16;
typedef unsigned int u32;
typedef unsigned short u16;

#define T_LEN 128
#define B_SZ  64
#define E_DIM 512
#define U_DIM 1024
#define G3    3072
#define BTU   (B_SZ * T_LEN * U_DIM)

typedef __attribute__((ext_vector_type(8))) __bf16 bf16x8;
typedef __attribute__((ext_vector_type(8))) u16  us8;
typedef __attribute__((ext_vector_type(4))) u16  us4;
typedef __attribute__((ext_vector_type(4))) f32  f32x4;

union F8 { us8 u; bf16x8 b; };

// workspace layout (bytes)
#define WS_USW 0u            // bf16 bits [256 blk][2 plane][24 row][1024 k] swizzled = 25165824 B
#define WS_HQ  25165824u     // u16 [2 buf][2 plane][2 dir][64 b][1024 k] = 1048576 B
#define WS_XG  26214400u     // bf16 [2][128][64 b][3072 col] = 100663296 B

// d_out scratch (overwritten by steps afterwards):
//   WT at byte 0        : u16 [2 d][2 p][3072 c][512 k] = 12582912 B
//   XE at byte 12582912 : u16 [2 p][64 b][128 t][512 k] = 16777216 B   (end 29.4MB < 34.1MB)

#define STEP_LDS 98304       // 96 KB U image; reduce region aliases it
#define XG_LDS   65536       // 2x32KB A/B hi-lo tiles

__device__ __forceinline__ u32 f32_to_bf16_rne(f32 x) {
  u32 b = __float_as_uint(x);
  return (b + 0x7fffu + ((b >> 16) & 1u)) >> 16;
}

// ---------------- U transpose + hi/lo split + per-block swizzled image ----------------
__global__ __launch_bounds__(256) void transpose_split(
    const f32* __restrict__ Uf, const f32* __restrict__ Ub, u16* __restrict__ USW)
{
  __shared__ f32 tile[32][33];
  const int d = blockIdx.z;
  const f32* Uw = d ? Ub : Uf;
  const int c0 = blockIdx.x * 32;
  const int k0 = blockIdx.y * 32;
  const int tx = threadIdx.x & 31;
  const int ty = threadIdx.x >> 5;
#pragma unroll
  for (int i = 0; i < 4; i++) {
    int kl = ty + i * 8;
    tile[kl][tx] = Uw[(size_t)(k0 + kl) * G3 + c0 + tx];
  }
  __syncthreads();
#pragma unroll
  for (int i = 0; i < 4; i++) {
    int cl = ty + i * 8;
    int c  = c0 + cl;
    f32 val = tile[tx][cl];
    int g = c >> 10, u = c & 1023;
    int blk = d * 128 + (u >> 3);
    int r   = g * 8 + (u & 7);
    u32 hib = f32_to_bf16_rne(val);
    f32 rem = val - __uint_as_float(hib << 16);
    u32 lob = f32_to_bf16_rne(rem);
    int k = k0 + tx;
    int slot = (k >> 3) ^ (r & 7);
    size_t base = ((size_t)blk * 2) * (24 * 1024);
    size_t off  = (size_t)r * 1024 + slot * 8 + (k & 7);
    USW[base + off] = (u16)hib;
    USW[base + (size_t)24 * 1024 + off] = (u16)lob;
  }
}

// ---------------- one-time W transpose+split: WT[d][p][col][k] ----------------
__global__ __launch_bounds__(256) void split_w(
    const f32* __restrict__ Wf, const f32* __restrict__ Wb, u16* __restrict__ WT)
{
  __shared__ f32 tile[32][33];
  const int d = blockIdx.z;
  const f32* W = d ? Wb : Wf;
  const int c0 = blockIdx.x * 32;
  const int k0 = blockIdx.y * 32;
  const int tx = threadIdx.x & 31;
  const int ty = threadIdx.x >> 5;
#pragma unroll
  for (int i = 0; i < 4; i++) {
    int kl = ty + i * 8;
    tile[kl][tx] = W[(size_t)(k0 + kl) * G3 + c0 + tx];
  }
  __syncthreads();
#pragma unroll
  for (int i = 0; i < 4; i++) {
    int cl = ty + i * 8;
    f32 val = tile[tx][cl];          // W[k0+tx][c0+cl]
    u32 bb = __float_as_uint(val);
    u16 hi = (u16)(bb >> 16);        // truncation-hi (matches r7 xg staging)
    f32 rem = val - __uint_as_float(bb & 0xffff0000u);
    u16 lo = (u16)f32_to_bf16_rne(rem);
    size_t ch = (((size_t)(d * 2 + 0) * G3) + c0 + cl) * 512 + k0 + tx;
    size_t cl_ = (((size_t)(d * 2 + 1) * G3) + c0 + cl) * 512 + k0 + tx;
    WT[ch] = hi;
    WT[cl_] = lo;
  }
}

// ---------------- one-time emb gather+split: XE[p][b][t][k] ----------------
__global__ __launch_bounds__(128) void split_emb(
    const int* __restrict__ tokens, const f32* __restrict__ emb, u16* __restrict__ XE)
{
  const int row = blockIdx.x;        // b*128 + t
  const int b = row >> 7, t = row & 127;
  const int tok = tokens[(size_t)b * T_LEN + t];
  const int k = threadIdx.x * 4;
  float4 v = *(const float4*)(emb + (size_t)tok * E_DIM + k);
  f32 vv[4] = {v.x, v.y, v.z, v.w};
  us4 h4, l4;
#pragma unroll
  for (int e = 0; e < 4; e++) {
    u32 bb = __float_as_uint(vv[e]);
    h4[e] = (u16)(bb >> 16);
    f32 rem = vv[e] - __uint_as_float(bb & 0xffff0000u);
    l4[e] = (u16)f32_to_bf16_rne(rem);
  }
  *(us4*)(XE + ((size_t)(0 * 64 + b) * 128 + t) * 512 + k) = h4;
  *(us4*)(XE + ((size_t)(1 * 64 + b) * 128 + t) * 512 + k) = l4;
}

// ---------------- input projection, MFMA, pre-split operands: XG[d][s][b][col] ----------------
__global__ __launch_bounds__(256) void xg_gemm_mfma2(
    const u16* __restrict__ XE,      // [2 p][64 b][128 t][512 k]
    const u16* __restrict__ WT,      // [2 d][2 p][3072 c][512 k]
    const f32* __restrict__ bif, const f32* __restrict__ bib,
    bf16* __restrict__ XG)
{
  extern __shared__ u16 XL[];        // Ash[2][128][64] | Bsh[2][128][64]
  u16* Ash = XL;
  u16* Bsh = XL + 16384;

  const int tid = threadIdx.x;
  const int n0 = blockIdx.x * 128;
  const int by = blockIdx.y;
  const int dir = by >> 6;
  const int s0 = (by & 63) * 2;
  const f32* bi = dir ? bib : bif;

  const int wv = tid >> 6;
  const int lane = tid & 63;
  const int arow = tid >> 1;
  const int akoff = (tid & 1) * 32;
  const int bcol = tid & 127;
  const int bkoff = (tid >> 7) * 32;

  const int srow = s0 + (arow >> 6);
  const int ab = arow & 63;
  const int at = dir ? srow : (T_LEN - 1 - srow);
  const u16* asrc_h = XE + ((size_t)(0 * 64 + ab) * 128 + at) * 512 + akoff;
  const u16* asrc_l = XE + ((size_t)(1 * 64 + ab) * 128 + at) * 512 + akoff;
  const u16* bsrc_h = WT + ((size_t)(dir * 2 + 0) * G3 + n0 + bcol) * 512 + bkoff;
  const u16* bsrc_l = WT + ((size_t)(dir * 2 + 1) * G3 + n0 + bcol) * 512 + bkoff;

  f32x4 acc[2][8];
#pragma unroll
  for (int mi = 0; mi < 2; mi++)
#pragma unroll
    for (int ni = 0; ni < 8; ni++) acc[mi][ni] = (f32x4){0.f, 0.f, 0.f, 0.f};

  for (int kk = 0; kk < 8; kk++) {
    __syncthreads();
#pragma unroll
    for (int g = 0; g < 4; g++) {
      us8 h8 = *(const us8*)(asrc_h + kk * 64 + g * 8);
      us8 l8 = *(const us8*)(asrc_l + kk * 64 + g * 8);
      int sl = (((akoff >> 3) + g) ^ (arow & 7)) * 8;
      *(us8*)&Ash[(size_t)arow * 64 + sl] = h8;
      *(us8*)&Ash[(size_t)(128 + arow) * 64 + sl] = l8;
    }
#pragma unroll
    for (int g = 0; g < 4; g++) {
      us8 h8 = *(const us8*)(bsrc_h + kk * 64 + g * 8);
      us8 l8 = *(const us8*)(bsrc_l + kk * 64 + g * 8);
      int sl = (((bkoff >> 3) + g) ^ (bcol & 7)) * 8;
      *(us8*)&Bsh[(size_t)bcol * 64 + sl] = h8;
      *(us8*)&Bsh[(size_t)(128 + bcol) * 64 + sl] = l8;
    }
    __syncthreads();
#pragma unroll
    for (int ks = 0; ks < 2; ks++) {
      F8 ah[2], al[2];
#pragma unroll
      for (int mi = 0; mi < 2; mi++) {
        int row = wv * 32 + mi * 16 + (lane & 15);
        int sl = ((ks * 4 + (lane >> 4)) ^ (row & 7)) * 8;
        ah[mi].u = *(const us8*)&Ash[(size_t)row * 64 + sl];
        al[mi].u = *(const us8*)&Ash[(size_t)(128 + row) * 64 + sl];
      }
#pragma unroll
      for (int ni = 0; ni < 8; ni++) {
        int col = ni * 16 + (lane & 15);
        int sl = ((ks * 4 + (lane >> 4)) ^ (col & 7)) * 8;
        F8 bh, bl;
        bh.u = *(const us8*)&Bsh[(size_t)col * 64 + sl];
        bl.u = *(const us8*)&Bsh[(size_t)(128 + col) * 64 + sl];
#pragma unroll
        for (int mi = 0; mi < 2; mi++) {
          acc[mi][ni] = __builtin_amdgcn_mfma_f32_16x16x32_bf16(ah[mi].b, bh.b, acc[mi][ni], 0, 0, 0);
          acc[mi][ni] = __builtin_amdgcn_mfma_f32_16x16x32_bf16(ah[mi].b, bl.b, acc[mi][ni], 0, 0, 0);
          acc[mi][ni] = __builtin_amdgcn_mfma_f32_16x16x32_bf16(al[mi].b, bh.b, acc[mi][ni], 0, 0, 0);
        }
      }
    }
  }
#pragma unroll
  for (int ni = 0; ni < 8; ni++) {
    int ncol = n0 + ni * 16 + (lane & 15);
    f32 bv = bi[ncol];
#pragma unroll
    for (int mi = 0; mi < 2; mi++) {
#pragma unroll
      for (int j = 0; j < 4; j++) {
        int row = wv * 32 + mi * 16 + (lane >> 4) * 4 + j;
        int sr = s0 + (row >> 6);
        int b = row & 63;
        XG[((size_t)(dir * T_LEN + sr) * B_SZ + b) * G3 + ncol] =
            __float2bfloat16(acc[mi][ni][j] + bv);
      }
    }
  }
}

// ---------------- one recurrence step, launched 128x ----------------
// 256 blocks (dir x 128 u-slices of 8) x 512 threads (8 waves: 4 b-tiles x 2 k-halves).
// H in hi/lo u16 planes [b][k] (2 contiguous 16B loads/iter, no unpack); plain rolled K-loop.
__global__ __launch_bounds__(512) void gru_step6(
    const u16* __restrict__ USW,
    u16* __restrict__ Hq2,           // [2 buf][2 plane][2 dir][64 b][1024 k]
    const u16* __restrict__ XG,      // bf16 bits [2][128][64 b][3072 col]
    const f32* __restrict__ bhf, const f32* __restrict__ bhb,
    f32* __restrict__ out, int s)
{
  extern __shared__ u16 Us[];        // [2][24][1024] swizzled (96 KB); red aliases it
  const int blk = blockIdx.x;
  const int dir = blk >> 7;
  const int su  = (blk & 127) * 8;
  const int tid = threadIdx.x;
  const int lane = tid & 63;
  const int w  = tid >> 6;
  const int nw = w & 3, kw = w >> 2;

  // stage per-block U image (swizzle baked into global layout)
  {
    const us8* src = (const us8*)(USW + (size_t)blk * (2 * 24 * 1024));
    us8* dst = (us8*)Us;
    for (int i = tid; i < 6144; i += 512) dst[i] = src[i];
  }

  const int bb = nw * 16 + (lane & 15);
  const int ko = (lane >> 4) * 8;
  const int kq = kw * 512;
  const int r0 = lane & 15;
  const int r1t = 16 + (lane & 15);
  const int r1 = r1t > 23 ? 23 : r1t;   // clamped rows land only in unread output rows

  const int rb_h0 = (0 * 24 + r0) * 2048;
  const int rb_l0 = (1 * 24 + r0) * 2048;
  const int rb_h1 = (0 * 24 + r1) * 2048;
  const int rb_l1 = (1 * 24 + r1) * 2048;
  const int sw0 = r0 & 7, sw1 = r1 & 7;

  const int bufr = s & 1, bufw = bufr ^ 1;
  const u16* HrHi = Hq2 + (size_t)(((bufr * 2 + 0) * 2 + dir) * 64 + bb) * 1024;
  const u16* HrLo = Hq2 + (size_t)(((bufr * 2 + 1) * 2 + dir) * 64 + bb) * 1024;

  __syncthreads();

  f32x4 acc0 = {0.f, 0.f, 0.f, 0.f};
  f32x4 acc1 = {0.f, 0.f, 0.f, 0.f};

  if (s) {
    for (int ks = 0; ks < 16; ks++) {
      const int kb = kq + ks * 32;
      const int slot = (kb >> 3) + (lane >> 4);
      F8 ah0, al0, ah1, al1;
      ah0.u = *(const us8*)((const char*)Us + rb_h0 + ((slot ^ sw0) << 4));
      al0.u = *(const us8*)((const char*)Us + rb_l0 + ((slot ^ sw0) << 4));
      ah1.u = *(const us8*)((const char*)Us + rb_h1 + ((slot ^ sw1) << 4));
      al1.u = *(const us8*)((const char*)Us + rb_l1 + ((slot ^ sw1) << 4));

      F8 bh_hi, bh_lo;
      bh_hi.u = *(const us8*)(HrHi + kb + ko);
      bh_lo.u = *(const us8*)(HrLo + kb + ko);

      acc0 = __builtin_amdgcn_mfma_f32_16x16x32_bf16(ah0.b, bh_hi.b, acc0, 0, 0, 0);
      acc0 = __builtin_amdgcn_mfma_f32_16x16x32_bf16(ah0.b, bh_lo.b, acc0, 0, 0, 0);
      acc0 = __builtin_amdgcn_mfma_f32_16x16x32_bf16(al0.b, bh_hi.b, acc0, 0, 0, 0);
      acc1 = __builtin_amdgcn_mfma_f32_16x16x32_bf16(ah1.b, bh_hi.b, acc1, 0, 0, 0);
      acc1 = __builtin_amdgcn_mfma_f32_16x16x32_bf16(ah1.b, bh_lo.b, acc1, 0, 0, 0);
      acc1 = __builtin_amdgcn_mfma_f32_16x16x32_bf16(al1.b, bh_hi.b, acc1, 0, 0, 0);
    }
  }

  // k-half reduction through LDS (reuse staging area — all Us reads done this launch)
  __syncthreads();
  f32* red = (f32*)Us;               // [4][64][8]
  if (kw == 1) {
    f32* p = red + (size_t)(nw * 64 + lane) * 8;
    *(f32x4*)p = acc0;
    *(f32x4*)(p + 4) = acc1;
  }
  __syncthreads();
  if (kw == 0) {
    const f32* p = red + (size_t)(nw * 64 + lane) * 8;
    f32x4 o0 = *(const f32x4*)p;
    f32x4 o1 = *(const f32x4*)(p + 4);
#pragma unroll
    for (int i = 0; i < 4; i++) { acc0[i] += o0[i]; acc1[i] += o1[i]; }

    f32 racc[4];
#pragma unroll
    for (int j = 0; j < 4; j++) racc[j] = __shfl_xor(acc0[j], 32);   // r-gate rows (8..15)

    if (lane < 32) {
      const int ul0 = (lane >> 4) * 4;     // 0 or 4
      const int u0 = su + ul0;
      const u16* xgp = XG + ((size_t)(dir * T_LEN + s) * B_SZ + bb) * G3;
      us4 gz = *(const us4*)(xgp + u0);
      us4 gr = *(const us4*)(xgp + 1024 + u0);
      us4 gh = *(const us4*)(xgp + 2048 + u0);
      us4 ohi = {0, 0, 0, 0}, olo = {0, 0, 0, 0};
      if (s) {
        ohi = *(const us4*)(HrHi + u0);
        olo = *(const us4*)(HrLo + u0);
      }
      const f32* bh = dir ? bhb : bhf;
      f32x4 hnv;
      us4 whi, wlo;
#pragma unroll
      for (int j = 0; j < 4; j++) {
        const int u = u0 + j;
        f32 hz = acc0[j] + bh[u];
        f32 hr = racc[j] + bh[1024 + u];
        f32 hh = acc1[j] + bh[2048 + u];
        f32 xz = __uint_as_float((u32)gz[j] << 16);
        f32 xr = __uint_as_float((u32)gr[j] << 16);
        f32 xh = __uint_as_float((u32)gh[j] << 16);
        f32 hold = __uint_as_float((u32)ohi[j] << 16) + __uint_as_float((u32)olo[j] << 16);

        f32 z  = 1.f / (1.f + expf(-(xz + hz)));
        f32 r  = 1.f / (1.f + expf(-(xr + hr)));
        f32 hc = tanhf(xh + r * hh);
        f32 hnew = z * hold + (1.f - z) * hc;

        u32 hib = f32_to_bf16_rne(hnew);
        f32 rem = hnew - __uint_as_float(hib << 16);
        u32 lob = f32_to_bf16_rne(rem);
        hnv[j] = hnew;
        whi[j] = (u16)hib;
        wlo[j] = (u16)lob;
      }
      u16* HwHi = Hq2 + (size_t)(((bufw * 2 + 0) * 2 + dir) * 64 + bb) * 1024;
      u16* HwLo = Hq2 + (size_t)(((bufw * 2 + 1) * 2 + dir) * 64 + bb) * 1024;
      *(us4*)(HwHi + u0) = whi;
      *(us4*)(HwLo + u0) = wlo;

      const int t = dir ? (T_LEN - 1 - s) : s;
      f32* op = out + ((size_t)bb * T_LEN + t) * U_DIM + u0;
      if (s < 64) {
        *(f32x4*)op = hnv;
      } else {
        f32x4 prev = *(const f32x4*)op;
#pragma unroll
        for (int j = 0; j < 4; j++) prev[j] += hnv[j];
        *(f32x4*)op = prev;
      }
      if (s == T_LEN - 1)
        *(f32x4*)(out + (size_t)BTU + (size_t)bb * 2048 + dir * 1024 + u0) = hnv;
    }
  }
}

extern "C" void kernel_launch(void* const* d_in, const int* in_sizes, int n_in,
                              void* d_out, int out_size, void* d_ws, size_t ws_size,
                              hipStream_t stream) {
  (void)in_sizes; (void)n_in; (void)out_size; (void)ws_size;
  const int* tokens = (const int*)d_in[0];
  const f32* emb = (const f32*)d_in[1];
  const f32* Wf  = (const f32*)d_in[2];
  const f32* Uf  = (const f32*)d_in[3];
  const f32* bif = (const f32*)d_in[4];
  const f32* bhf = (const f32*)d_in[5];
  const f32* Wb  = (const f32*)d_in[6];
  const f32* Ub  = (const f32*)d_in[7];
  const f32* bib = (const f32*)d_in[8];
  const f32* bhb = (const f32*)d_in[9];

  char* ws = (char*)d_ws;
  u16*  USW = (u16*)(ws + WS_USW);
  u16*  Hq2 = (u16*)(ws + WS_HQ);
  bf16* XG  = (bf16*)(ws + WS_XG);
  f32*  out = (f32*)d_out;

  // d_out as prep scratch (fully overwritten by the recurrence afterwards)
  u16* WT = (u16*)d_out;
  u16* XE = (u16*)((char*)d_out + 12582912);

  split_w<<<dim3(96, 16, 2), 256, 0, stream>>>(Wf, Wb, WT);
  split_emb<<<8192, 128, 0, stream>>>(tokens, emb, XE);
  transpose_split<<<dim3(96, 32, 2), 256, 0, stream>>>(Uf, Ub, USW);

  hipFuncSetAttribute((const void*)xg_gemm_mfma2,
                      hipFuncAttributeMaxDynamicSharedMemorySize, XG_LDS);
  xg_gemm_mfma2<<<dim3(24, 128), 256, XG_LDS, stream>>>(XE, WT, bif, bib, XG);

  hipFuncSetAttribute((const void*)gru_step6,
                      hipFuncAttributeMaxDynamicSharedMemorySize, STEP_LDS);
  for (int s = 0; s < T_LEN; s++)
    gru_step6<<<256, 512, STEP_LDS, stream>>>(USW, Hq2, (const u16*)XG, bhf, bhb, out, s);
}